// Round 1
// 142.848 us; speedup vs baseline: 1.1548x; 1.1548x over previous
//
#include <hip/hip_runtime.h>
#include <hip/hip_bf16.h>
#include <math.h>

#define NLAT 255
#define NPIX 49152
#define PI_F 3.14159265358979323846f

typedef _Float16 half_t;
typedef half_t half8 __attribute__((ext_vector_type(8)));   // A/B frag: 4 VGPRs
typedef float  f32x4 __attribute__((ext_vector_type(4)));   // C/D frag

// ---------------- ring geometry (NSIDE=64, compile-time closed forms) -------
__device__ __forceinline__ void ring_params(int t, int& n, int& roff) {
    if (t < 63)        { n = 4 * (t + 1); roff = 2 * t * (t + 1); }
    else if (t <= 191) { n = 256;         roff = 8064 + 256 * (t - 63); }
    else               { int w = 255 - t; n = 4 * w; roff = 49152 - 2 * w * (w + 1); }
}

// ============ merged prep kernel ============================================
// blocks [0,768):        pct[m][l][t] -> pctT[m][t][l] fp16 (t padded to 256)
// blocks [768,5376):     x[bc][l][m]  -> xh[c][m][l/8][bc][l%8] fp16
// blocks [5376,11520):   build twiddle W[pix][192] fp16:
//   W[p][2m]=sc_m*cos(m*phi), W[p][2m+1]=-sc_m*sin(m*phi), phi=2pi p/n+alpha_t
//   folds: phase offset (off=alpha*m), irfft interior x2, m-crop (sc=0),
//   Nyquist (sc=1; Re{X e^{i(n/2)phi}} form is exact incl. alpha).
__global__ __launch_bounds__(256) void k_prep(
        const float* __restrict__ pct,
        const float* __restrict__ xr, const float* __restrict__ xi,
        half_t* __restrict__ pctT, half_t* __restrict__ xh,
        half_t* __restrict__ W) {
    __shared__ float smem[96 * 33];
    const int bx  = blockIdx.x;
    const int tid = threadIdx.x;

    if (bx < 768) {                     // ---- pct transpose ----
        const int m = bx >> 3, t0 = (bx & 7) * 32;
        for (int idx = tid; idx < 96 * 32; idx += 256) {
            int l = idx >> 5, tt = idx & 31, t = t0 + tt;
            smem[l * 33 + tt] = (t < NLAT) ? pct[((size_t)m * 96 + l) * NLAT + t] : 0.f;
        }
        __syncthreads();
        for (int idx = tid; idx < 96 * 32; idx += 256) {
            int tt = idx / 96, l = idx - tt * 96;
            pctT[((size_t)m * 256 + t0 + tt) * 96 + l] = (half_t)smem[l * 33 + tt];
        }
    } else if (bx < 5376) {             // ---- x pack/transpose ----
        const int id  = bx - 768;
        const int z   = id / 768;       // comp*3 + mtile
        const int rem = id - z * 768;
        const int l   = rem % 96;
        const int bc0 = (rem / 96) * 32;
        const int comp = z / 3, m0 = (z % 3) * 32;
        const float* in = comp ? xi : xr;
        const int tx = tid & 31, ty = tid >> 5;
#pragma unroll
        for (int j = 0; j < 4; ++j) {
            int bcl = ty + j * 8;
            smem[bcl * 33 + tx] = in[((size_t)(bc0 + bcl) * 96 + l) * 96 + m0 + tx];
        }
        __syncthreads();
#pragma unroll
        for (int j = 0; j < 4; ++j) {
            int ml = ty + j * 8;
            xh[((((size_t)(comp * 96 + m0 + ml)) * 12 + (l >> 3)) * 256 + bc0 + tx) * 8
               + (l & 7)] = (half_t)smem[tx * 33 + ml];
        }
    } else {                            // ---- twiddle W ----
        int gid   = (bx - 5376) * 256 + tid;
        int chunk = gid & 31;           // k-chunk of 8 (4 m); only 0..23 used
        int pix   = gid >> 5;
        if (chunk >= 24 || pix >= NPIX) return;

        int t, p;
        if (pix < 8064) {                                   // north cap
            int tt = (int)((sqrtf((float)(2 * pix + 1)) - 1.0f) * 0.5f);
            while (2 * tt * (tt + 1) > pix) --tt;
            while (2 * (tt + 1) * (tt + 2) <= pix) ++tt;
            t = tt; p = pix - 2 * tt * (tt + 1);
        } else if (pix < 41088) {                           // equatorial
            t = 63 + ((pix - 8064) >> 8); p = (pix - 8064) & 255;
        } else {                                            // south cap
            int r = NPIX - 1 - pix;
            int tt = (int)((sqrtf((float)(2 * r + 1)) - 1.0f) * 0.5f);
            while (2 * tt * (tt + 1) > r) --tt;
            while (2 * (tt + 1) * (tt + 2) <= r) ++tt;
            int w = tt + 1;
            t = 254 - tt;
            p = pix - (NPIX - 2 * w * (w + 1));
        }
        int n, roff; ring_params(t, n, roff);
        const int n2 = n >> 1;
        float alpha = (t < 63)   ? PI_F / (4.0f * (float)(t + 1))
                    : (t <= 191) ? (((t - 62) & 1) ? PI_F / 256.0f : 0.0f)
                    :              PI_F / (4.0f * (float)(255 - t));
        float phi = 6.28318530717958647692f * (float)p / (float)n + alpha;

        int m0 = chunk * 4;
        float c, s, cd, sd;
        __sincosf((float)m0 * phi, &s, &c);
        __sincosf(phi, &sd, &cd);
        half8 v;
#pragma unroll
        for (int j = 0; j < 4; ++j) {
            int m = m0 + j;
            float sc = (m == 0) ? 1.f : (m < n2) ? 2.f : (m == n2) ? 1.f : 0.f;
            v[2 * j]     = (half_t)(sc * c);
            v[2 * j + 1] = (half_t)(-sc * s);
            float cn = c * cd - s * sd; s = s * cd + c * sd; c = cn;
        }
        *(half8*)(W + (size_t)pix * 192 + chunk * 8) = v;
    }
}

// ============ stage 1: Legendre GEMMs (MFMA) ================================
// For m-group of 4: C[t][bc] = sum_l pctT[m][t][l] * xh[c][m][l][bc], K=96.
// Block tile M=64 x N=32, 4 waves (2 in t, 2 in bc), wave tile 32x16.
// Epilogue packs 4m x {re,im} = 8 consecutive k into one 16B Xp store.
__global__ __launch_bounds__(256) void k_leg(
        const half_t* __restrict__ pctT, const half_t* __restrict__ xh,
        half_t* __restrict__ Xp) {
    const int mg  = blockIdx.x;          // 0..23
    const int t0  = blockIdx.y * 64;
    const int bc0 = blockIdx.z * 32;
    const int wid = threadIdx.x >> 6, lane = threadIdx.x & 63;
    const int wm = wid & 1, wn = wid >> 1;
    const int row = lane & 15, quad = lane >> 4;
    const int tbase = t0 + wm * 32;
    const int bc    = bc0 + wn * 16 + row;

    f32x4 acc[4][2][2];                  // [mi][comp][mt]
#pragma unroll
    for (int a = 0; a < 4; ++a)
#pragma unroll
        for (int b = 0; b < 2; ++b)
#pragma unroll
            for (int d = 0; d < 2; ++d) acc[a][b][d] = (f32x4)0.f;

#pragma unroll
    for (int k0 = 0; k0 < 96; k0 += 32) {
        const int kA = k0 + quad * 8;
        half8 af[4][2], bf[4][2];
#pragma unroll
        for (int mi = 0; mi < 4; ++mi) {
            const int m = mg * 4 + mi;
#pragma unroll
            for (int mt = 0; mt < 2; ++mt)
                af[mi][mt] = *(const half8*)(pctT +
                    ((size_t)m * 256 + tbase + mt * 16 + row) * 96 + kA);
#pragma unroll
            for (int c = 0; c < 2; ++c)
                bf[mi][c] = *(const half8*)(xh +
                    ((((size_t)(c * 96 + m)) * 12 + (k0 >> 3) + quad) * 256 + bc) * 8);
        }
#pragma unroll
        for (int mi = 0; mi < 4; ++mi)
#pragma unroll
            for (int c = 0; c < 2; ++c)
#pragma unroll
                for (int mt = 0; mt < 2; ++mt)
                    acc[mi][c][mt] = __builtin_amdgcn_mfma_f32_16x16x32_f16(
                        af[mi][mt], bf[mi][c], acc[mi][c][mt], 0, 0, 0);
    }

#pragma unroll
    for (int mt = 0; mt < 2; ++mt)
#pragma unroll
        for (int r = 0; r < 4; ++r) {
            const int t = tbase + mt * 16 + quad * 4 + r;
            half8 v;
#pragma unroll
            for (int mi = 0; mi < 4; ++mi) {
                v[2 * mi]     = (half_t)acc[mi][0][mt][r];
                v[2 * mi + 1] = (half_t)acc[mi][1][mt][r];
            }
            *(half8*)(Xp + (((size_t)t * 24 + mg) * 256 + bc) * 8) = v;
        }
}

// ============ stage 2: unified ring DFT (MFMA), all 255 rings ===============
// out[p][bc] = sum_k W[roff+p][k] * Xp[t][k][bc].
// v2: one block covers the FULL bc=256 (z-split removed -> W fetched once,
// not 4x), wave tile 64p x 64bc -> acc[4][4], 16 MFMA per 8 loads per k-step
// (2.5x compute density), k-loop fully unrolled for ks==6 rings (t in
// [39,215], the bulk of work; W is zero past Nyquist so full-K is exact).
// Grid flattened to 1020 blocks with bijective XCD swizzle (1020 = 8*127+4)
// so a ring's 4 p-tiles share its Xp row in one XCD's L2.
__device__ __forceinline__ void dft_step(int kk,
        const half_t* __restrict__ wb, const half_t* __restrict__ xpb,
        f32x4 acc[4][4]) {
    half8 a[4], b[4];
#pragma unroll
    for (int bn = 0; bn < 4; ++bn)
        b[bn] = *(const half8*)(xpb + kk * 8192 + bn * 128);   // bn*16 rows * 8
#pragma unroll
    for (int pi = 0; pi < 4; ++pi)
        a[pi] = *(const half8*)(wb + kk * 32 + pi * 3072);     // pi*16 rows * 192
#pragma unroll
    for (int pi = 0; pi < 4; ++pi)
#pragma unroll
        for (int bn = 0; bn < 4; ++bn)
            acc[pi][bn] = __builtin_amdgcn_mfma_f32_16x16x32_f16(
                a[pi], b[bn], acc[pi][bn], 0, 0, 0);
}

__global__ __launch_bounds__(256) void k_dft(
        const half_t* __restrict__ W, const half_t* __restrict__ Xp,
        float* __restrict__ out) {
    // bijective XCD swizzle: nwg=1020, q=127, r=4. Consecutive wg (= t*4+y,
    // y fastest) land on the same XCD -> Xp t-row fetched once per XCD.
    const int bid = blockIdx.x;
    const int xcd = bid & 7, sub = bid >> 3;
    const int wg  = (xcd < 4 ? xcd * 128 : 512 + (xcd - 4) * 127) + sub;
    const int t   = wg >> 2;
    const int p0  = (wg & 3) * 64;
    int n, roff; ring_params(t, n, roff);
    if (p0 >= n) return;

    const int wid = threadIdx.x >> 6, lane = threadIdx.x & 63;
    const int row = lane & 15, quad = lane >> 4;

    const half_t* wb  = W  + (size_t)(roff + p0 + row) * 192 + quad * 8;
    const half_t* xpb = Xp + (((size_t)t * 24 + quad) * 256 + wid * 64 + row) * 8;

    const int mh = min(95, n >> 1);
    const int ks = (2 * (mh + 1) + 31) >> 5;   // 1..6 active 32-wide k-steps

    f32x4 acc[4][4];                     // [pi][bn]
#pragma unroll
    for (int i = 0; i < 4; ++i)
#pragma unroll
        for (int j = 0; j < 4; ++j) acc[i][j] = (f32x4)0.f;

    if (ks == 6) {                       // bulk path: full unroll, max ILP
#pragma unroll
        for (int kk = 0; kk < 6; ++kk) dft_step(kk, wb, xpb, acc);
    } else {                             // small cap rings only
        for (int kk = 0; kk < ks; ++kk) dft_step(kk, wb, xpb, acc);
    }

#pragma unroll
    for (int pi = 0; pi < 4; ++pi) {
        const int p = p0 + pi * 16 + quad * 4;
        if (p < n) {                     // n%4==0 -> whole float4 in-bounds
#pragma unroll
            for (int bn = 0; bn < 4; ++bn) {
                const int bc = wid * 64 + bn * 16 + row;
                float4 v = make_float4(acc[pi][bn][0], acc[pi][bn][1],
                                       acc[pi][bn][2], acc[pi][bn][3]);
                *(float4*)(out + (size_t)bc * NPIX + roff + p) = v;
            }
        }
    }
}

// ---------------- launcher --------------------------------------------------
extern "C" void kernel_launch(void* const* d_in, const int* in_sizes, int n_in,
                              void* d_out, int out_size, void* d_ws, size_t ws_size,
                              hipStream_t stream) {
    const float* xr  = (const float*)d_in[0];   // (4,64,96,96)
    const float* xi  = (const float*)d_in[1];   // (4,64,96,96)
    const float* pct = (const float*)d_in[2];   // (96,96,255)
    // d_in[3] (offset) recomputed analytically: off[t][m] = alpha_t * m
    float* out = (float*)d_out;                 // (4,64,49152)

    char* ws = (char*)d_ws;
    half_t* W    = (half_t*)ws;                         // (NPIX+64)*192 halfs
    half_t* pctT = (half_t*)(ws + 18923520);            // 96*256*96
    half_t* xh   = (half_t*)(ws + 18923520 + 4718592);  // 2*96*12*256*8
    half_t* Xp   = (half_t*)(ws + 18923520 + 4718592 + 9437184); // 256*24*256*8

    k_prep<<<dim3(11520), 256, 0, stream>>>(pct, xr, xi, pctT, xh, W);
    k_leg <<<dim3(24, 4, 8), 256, 0, stream>>>(pctT, xh, Xp);
    k_dft <<<dim3(1020), 256, 0, stream>>>(W, Xp, out);
}

// Round 2
// 136.451 us; speedup vs baseline: 1.2089x; 1.0469x over previous
//
#include <hip/hip_runtime.h>
#include <hip/hip_bf16.h>
#include <math.h>

#define NLAT 255
#define NPIX 49152
#define PI_F 3.14159265358979323846f

typedef _Float16 half_t;
typedef half_t half8 __attribute__((ext_vector_type(8)));   // A/B frag: 4 VGPRs
typedef float  f32x4 __attribute__((ext_vector_type(4)));   // C/D frag

// ---------------- ring geometry (NSIDE=64, compile-time closed forms) -------
__device__ __forceinline__ void ring_params(int t, int& n, int& roff) {
    if (t < 63)        { n = 4 * (t + 1); roff = 2 * t * (t + 1); }
    else if (t <= 191) { n = 256;         roff = 8064 + 256 * (t - 63); }
    else               { int w = 255 - t; n = 4 * w; roff = 49152 - 2 * w * (w + 1); }
}

__device__ __forceinline__ float ring_alpha(int t) {
    return (t < 63)   ? PI_F / (4.0f * (float)(t + 1))
         : (t <= 191) ? ((((t - 62) & 1)) ? PI_F / 256.0f : 0.0f)
         :              PI_F / (4.0f * (float)(255 - t));
}

// ============ merged prep kernel ============================================
// blocks [0,768):      pct[m][l][t] -> pctT[m][t][l] fp16 (t padded to 256)
// blocks [768,5376):   x[bc][l][m]  -> xh[c][m][l/8][bc][l%8] fp16
// (twiddle table removed: k_dft now generates twiddles in-register)
__global__ __launch_bounds__(256) void k_prep(
        const float* __restrict__ pct,
        const float* __restrict__ xr, const float* __restrict__ xi,
        half_t* __restrict__ pctT, half_t* __restrict__ xh) {
    __shared__ float smem[96 * 33];
    const int bx  = blockIdx.x;
    const int tid = threadIdx.x;

    if (bx < 768) {                     // ---- pct transpose ----
        const int m = bx >> 3, t0 = (bx & 7) * 32;
        for (int idx = tid; idx < 96 * 32; idx += 256) {
            int l = idx >> 5, tt = idx & 31, t = t0 + tt;
            smem[l * 33 + tt] = (t < NLAT) ? pct[((size_t)m * 96 + l) * NLAT + t] : 0.f;
        }
        __syncthreads();
        for (int idx = tid; idx < 96 * 32; idx += 256) {
            int tt = idx / 96, l = idx - tt * 96;
            pctT[((size_t)m * 256 + t0 + tt) * 96 + l] = (half_t)smem[l * 33 + tt];
        }
    } else {                            // ---- x pack/transpose ----
        const int id  = bx - 768;
        const int z   = id / 768;       // comp*3 + mtile
        const int rem = id - z * 768;
        const int l   = rem % 96;
        const int bc0 = (rem / 96) * 32;
        const int comp = z / 3, m0 = (z % 3) * 32;
        const float* in = comp ? xi : xr;
        const int tx = tid & 31, ty = tid >> 5;
#pragma unroll
        for (int j = 0; j < 4; ++j) {
            int bcl = ty + j * 8;
            smem[bcl * 33 + tx] = in[((size_t)(bc0 + bcl) * 96 + l) * 96 + m0 + tx];
        }
        __syncthreads();
#pragma unroll
        for (int j = 0; j < 4; ++j) {
            int ml = ty + j * 8;
            xh[((((size_t)(comp * 96 + m0 + ml)) * 12 + (l >> 3)) * 256 + bc0 + tx) * 8
               + (l & 7)] = (half_t)smem[tx * 33 + ml];
        }
    }
}

// ============ stage 1: Legendre GEMMs (MFMA) ================================
// For m-group of 4: C[t][bc] = sum_l pctT[m][t][l] * xh[c][m][l][bc], K=96.
// Block tile M=64 x N=32, 4 waves (2 in t, 2 in bc), wave tile 32x16.
// Epilogue packs 4m x {re,im} = 8 consecutive k into one 16B Xp store.
__global__ __launch_bounds__(256) void k_leg(
        const half_t* __restrict__ pctT, const half_t* __restrict__ xh,
        half_t* __restrict__ Xp) {
    const int mg  = blockIdx.x;          // 0..23
    const int t0  = blockIdx.y * 64;
    const int bc0 = blockIdx.z * 32;
    const int wid = threadIdx.x >> 6, lane = threadIdx.x & 63;
    const int wm = wid & 1, wn = wid >> 1;
    const int row = lane & 15, quad = lane >> 4;
    const int tbase = t0 + wm * 32;
    const int bc    = bc0 + wn * 16 + row;

    f32x4 acc[4][2][2];                  // [mi][comp][mt]
#pragma unroll
    for (int a = 0; a < 4; ++a)
#pragma unroll
        for (int b = 0; b < 2; ++b)
#pragma unroll
            for (int d = 0; d < 2; ++d) acc[a][b][d] = (f32x4)0.f;

#pragma unroll
    for (int k0 = 0; k0 < 96; k0 += 32) {
        const int kA = k0 + quad * 8;
        half8 af[4][2], bf[4][2];
#pragma unroll
        for (int mi = 0; mi < 4; ++mi) {
            const int m = mg * 4 + mi;
#pragma unroll
            for (int mt = 0; mt < 2; ++mt)
                af[mi][mt] = *(const half8*)(pctT +
                    ((size_t)m * 256 + tbase + mt * 16 + row) * 96 + kA);
#pragma unroll
            for (int c = 0; c < 2; ++c)
                bf[mi][c] = *(const half8*)(xh +
                    ((((size_t)(c * 96 + m)) * 12 + (k0 >> 3) + quad) * 256 + bc) * 8);
        }
#pragma unroll
        for (int mi = 0; mi < 4; ++mi)
#pragma unroll
            for (int c = 0; c < 2; ++c)
#pragma unroll
                for (int mt = 0; mt < 2; ++mt)
                    acc[mi][c][mt] = __builtin_amdgcn_mfma_f32_16x16x32_f16(
                        af[mi][mt], bf[mi][c], acc[mi][c][mt], 0, 0, 0);
    }

#pragma unroll
    for (int mt = 0; mt < 2; ++mt)
#pragma unroll
        for (int r = 0; r < 4; ++r) {
            const int t = tbase + mt * 16 + quad * 4 + r;
            half8 v;
#pragma unroll
            for (int mi = 0; mi < 4; ++mi) {
                v[2 * mi]     = (half_t)acc[mi][0][mt][r];
                v[2 * mi + 1] = (half_t)acc[mi][1][mt][r];
            }
            *(half8*)(Xp + (((size_t)t * 24 + mg) * 256 + bc) * 8) = v;
        }
}

// ============ stage 2: unified ring DFT (MFMA), all 255 rings ===============
// out[p][bc] = sum_k W_k(p) * Xp[t][k][bc], W generated IN-REGISTER:
//   W[p][2m] = sc_m*cos(m*phi_p), W[p][2m+1] = -sc_m*sin(m*phi_p),
//   phi_p = 2pi p/n + alpha_t; sc folds irfft interior x2 / m-crop / Nyquist.
// Each lane owns 4 p-rows (pi); per k-step the 4 m-values advance by a fixed
// rotation e^{i*16*phi} (and e^{i*phi} within the half8) -> pure FMA chain
// feeding the MFMA A-fragment.  Removes the 18.9MB W table (write+read) and
// the pixel->(t,p) decode.  Block covers full bc=256; wave tile 64p x 64bc.
// Grid flattened to 1020 blocks with bijective XCD swizzle (1020 = 8*127+4)
// so a ring's 4 p-tiles share its Xp row in one XCD's L2.
__global__ __launch_bounds__(256) void k_dft(
        const half_t* __restrict__ Xp, float* __restrict__ out) {
    const int bid = blockIdx.x;
    const int xcd = bid & 7, sub = bid >> 3;
    const int wg  = (xcd < 4 ? xcd * 128 : 512 + (xcd - 4) * 127) + sub;
    const int t   = wg >> 2;
    const int p0  = (wg & 3) * 64;
    int n, roff; ring_params(t, n, roff);
    if (p0 >= n) return;

    const int wid = threadIdx.x >> 6, lane = threadIdx.x & 63;
    const int row = lane & 15, quad = lane >> 4;
    const int mq  = quad * 4;            // first m of this lane's half8

    const half_t* xpb = Xp + (((size_t)t * 24 + quad) * 256 + wid * 64 + row) * 8;

    const int n2 = n >> 1;
    const int mh = min(95, n2);
    const int ks = (2 * (mh + 1) + 31) >> 5;   // 1..6 active 32-wide k-steps

    // per-pi twiddle state: current (cos,sin) at m = mq + 16*kk, plus the
    // per-j delta e^{i*phi} and per-kk delta e^{i*16*phi}
    const float alpha = ring_alpha(t);
    const float invn  = 1.0f / (float)n;
    float cc[4], ss[4], d1c[4], d1s[4], d16c[4], d16s[4];
#pragma unroll
    for (int pi = 0; pi < 4; ++pi) {
        float phi = 6.28318530717958647692f * (float)(p0 + pi * 16 + row) * invn
                  + alpha;
        __sincosf(phi, &d1s[pi], &d1c[pi]);
        __sincosf(16.0f * phi, &d16s[pi], &d16c[pi]);
        __sincosf((float)mq * phi, &ss[pi], &cc[pi]);
    }

    f32x4 acc[4][4];                     // [pi][bn]
#pragma unroll
    for (int i = 0; i < 4; ++i)
#pragma unroll
        for (int j = 0; j < 4; ++j) acc[i][j] = (f32x4)0.f;

    auto step = [&](int kk) {
        half8 b[4];
#pragma unroll
        for (int bn = 0; bn < 4; ++bn)
            b[bn] = *(const half8*)(xpb + kk * 8192 + bn * 128);
        half8 af[4];
#pragma unroll
        for (int pi = 0; pi < 4; ++pi) {
            float c = cc[pi], s = ss[pi];
            half8 a;
#pragma unroll
            for (int j = 0; j < 4; ++j) {
                int m = kk * 16 + mq + j;
                float sc = (m == 0) ? 1.f : (m < n2) ? 2.f : (m == n2) ? 1.f : 0.f;
                a[2 * j]     = (half_t)(sc * c);
                a[2 * j + 1] = (half_t)(-sc * s);
                float cn = c * d1c[pi] - s * d1s[pi];
                s = s * d1c[pi] + c * d1s[pi];
                c = cn;
            }
            float cn = cc[pi] * d16c[pi] - ss[pi] * d16s[pi];
            ss[pi] = ss[pi] * d16c[pi] + cc[pi] * d16s[pi];
            cc[pi] = cn;
            af[pi] = a;
        }
#pragma unroll
        for (int pi = 0; pi < 4; ++pi)
#pragma unroll
            for (int bn = 0; bn < 4; ++bn)
                acc[pi][bn] = __builtin_amdgcn_mfma_f32_16x16x32_f16(
                    af[pi], b[bn], acc[pi][bn], 0, 0, 0);
    };

    if (ks == 6) {                       // bulk path: full unroll, max ILP
#pragma unroll
        for (int kk = 0; kk < 6; ++kk) step(kk);
    } else {                             // small cap rings only
        for (int kk = 0; kk < ks; ++kk) step(kk);
    }

#pragma unroll
    for (int pi = 0; pi < 4; ++pi) {
        const int p = p0 + pi * 16 + quad * 4;
        if (p < n) {                     // n%4==0 -> whole float4 in-bounds
#pragma unroll
            for (int bn = 0; bn < 4; ++bn) {
                const int bc = wid * 64 + bn * 16 + row;
                float4 v = make_float4(acc[pi][bn][0], acc[pi][bn][1],
                                       acc[pi][bn][2], acc[pi][bn][3]);
                *(float4*)(out + (size_t)bc * NPIX + roff + p) = v;
            }
        }
    }
}

// ---------------- launcher --------------------------------------------------
extern "C" void kernel_launch(void* const* d_in, const int* in_sizes, int n_in,
                              void* d_out, int out_size, void* d_ws, size_t ws_size,
                              hipStream_t stream) {
    const float* xr  = (const float*)d_in[0];   // (4,64,96,96)
    const float* xi  = (const float*)d_in[1];   // (4,64,96,96)
    const float* pct = (const float*)d_in[2];   // (96,96,255)
    // d_in[3] (offset) recomputed analytically: off[t][m] = alpha_t * m
    float* out = (float*)d_out;                 // (4,64,49152)

    char* ws = (char*)d_ws;
    half_t* pctT = (half_t*)ws;                          // 96*256*96 halfs
    half_t* xh   = (half_t*)(ws + 4718592);              // 2*96*12*256*8 halfs
    half_t* Xp   = (half_t*)(ws + 4718592 + 9437184);    // 256*24*256*8 halfs

    k_prep<<<dim3(5376), 256, 0, stream>>>(pct, xr, xi, pctT, xh);
    k_leg <<<dim3(24, 4, 8), 256, 0, stream>>>(pctT, xh, Xp);
    k_dft <<<dim3(1020), 256, 0, stream>>>(Xp, out);
}

// Round 3
// 133.801 us; speedup vs baseline: 1.2329x; 1.0198x over previous
//
#include <hip/hip_runtime.h>
#include <hip/hip_bf16.h>
#include <math.h>

#define NLAT 255
#define NPIX 49152
#define PI_F 3.14159265358979323846f

typedef _Float16 half_t;
typedef half_t half8 __attribute__((ext_vector_type(8)));   // A/B frag: 4 VGPRs
typedef half_t half2_t __attribute__((ext_vector_type(2)));
typedef float  f32x4 __attribute__((ext_vector_type(4)));   // C/D frag

// ---------------- ring geometry (NSIDE=64, compile-time closed forms) -------
__device__ __forceinline__ void ring_params(int t, int& n, int& roff) {
    if (t < 63)        { n = 4 * (t + 1); roff = 2 * t * (t + 1); }
    else if (t <= 191) { n = 256;         roff = 8064 + 256 * (t - 63); }
    else               { int w = 255 - t; n = 4 * w; roff = 49152 - 2 * w * (w + 1); }
}

__device__ __forceinline__ float ring_alpha(int t) {
    return (t < 63)   ? PI_F / (4.0f * (float)(t + 1))
         : (t <= 191) ? ((((t - 62) & 1)) ? PI_F / 256.0f : 0.0f)
         :              PI_F / (4.0f * (float)(255 - t));
}

// ============ merged prep kernel ============================================
// blocks [0,768):      pct[m][l][t] -> pctT[m][t][l] fp16 (t padded to 256)
// blocks [768,5376):   x[bc][l][m]  -> xh[c][m][l/8][bc][l%8] fp16
__global__ __launch_bounds__(256) void k_prep(
        const float* __restrict__ pct,
        const float* __restrict__ xr, const float* __restrict__ xi,
        half_t* __restrict__ pctT, half_t* __restrict__ xh) {
    __shared__ float smem[96 * 33];
    const int bx  = blockIdx.x;
    const int tid = threadIdx.x;

    if (bx < 768) {                     // ---- pct transpose ----
        const int m = bx >> 3, t0 = (bx & 7) * 32;
        for (int idx = tid; idx < 96 * 32; idx += 256) {
            int l = idx >> 5, tt = idx & 31, t = t0 + tt;
            smem[l * 33 + tt] = (t < NLAT) ? pct[((size_t)m * 96 + l) * NLAT + t] : 0.f;
        }
        __syncthreads();
        for (int idx = tid; idx < 96 * 32; idx += 256) {
            int tt = idx / 96, l = idx - tt * 96;
            pctT[((size_t)m * 256 + t0 + tt) * 96 + l] = (half_t)smem[l * 33 + tt];
        }
    } else {                            // ---- x pack/transpose ----
        const int id  = bx - 768;
        const int z   = id / 768;       // comp*3 + mtile
        const int rem = id - z * 768;
        const int l   = rem % 96;
        const int bc0 = (rem / 96) * 32;
        const int comp = z / 3, m0 = (z % 3) * 32;
        const float* in = comp ? xi : xr;
        const int tx = tid & 31, ty = tid >> 5;
#pragma unroll
        for (int j = 0; j < 4; ++j) {
            int bcl = ty + j * 8;
            smem[bcl * 33 + tx] = in[((size_t)(bc0 + bcl) * 96 + l) * 96 + m0 + tx];
        }
        __syncthreads();
#pragma unroll
        for (int j = 0; j < 4; ++j) {
            int ml = ty + j * 8;
            xh[((((size_t)(comp * 96 + m0 + ml)) * 12 + (l >> 3)) * 256 + bc0 + tx) * 8
               + (l & 7)] = (half_t)smem[tx * 33 + ml];
        }
    }
}

// ============ stage 1: Legendre GEMMs (MFMA) ================================
// For m-group of 4: C[t][bc] = sum_l pctT[m][t][l] * xh[c][m][l][bc], K=96.
// Block tile M=64 x N=32, 4 waves (2 in t, 2 in bc), wave tile 32x16.
// v3: grid flattened to 768 with chunked XCD mapping: 96 consecutive wg per
// XCD = 3 complete mg groups (working set 2.4MB < 4MB L2), z fastest ->
// A-tile (mg,y) reused by 8 consecutive wg, B (mg,z) by the 4 y's, all on
// one XCD -> pctT/xh fetched from HBM once instead of 8x/4x.
__global__ __launch_bounds__(256) void k_leg(
        const half_t* __restrict__ pctT, const half_t* __restrict__ xh,
        half_t* __restrict__ Xp) {
    const int b   = blockIdx.x;
    const int wg  = (b & 7) * 96 + (b >> 3);   // bijective, 768 = 8*96
    const int mg  = wg >> 5;                   // 0..23
    const int rem = wg & 31;
    const int t0  = (rem >> 3) * 64;
    const int bc0 = (rem & 7) * 32;
    const int wid = threadIdx.x >> 6, lane = threadIdx.x & 63;
    const int wm = wid & 1, wn = wid >> 1;
    const int row = lane & 15, quad = lane >> 4;
    const int tbase = t0 + wm * 32;
    const int bc    = bc0 + wn * 16 + row;

    f32x4 acc[4][2][2];                  // [mi][comp][mt]
#pragma unroll
    for (int a = 0; a < 4; ++a)
#pragma unroll
        for (int bb = 0; bb < 2; ++bb)
#pragma unroll
            for (int d = 0; d < 2; ++d) acc[a][bb][d] = (f32x4)0.f;

#pragma unroll
    for (int k0 = 0; k0 < 96; k0 += 32) {
        const int kA = k0 + quad * 8;
        half8 af[4][2], bf[4][2];
#pragma unroll
        for (int mi = 0; mi < 4; ++mi) {
            const int m = mg * 4 + mi;
#pragma unroll
            for (int mt = 0; mt < 2; ++mt)
                af[mi][mt] = *(const half8*)(pctT +
                    ((size_t)m * 256 + tbase + mt * 16 + row) * 96 + kA);
#pragma unroll
            for (int c = 0; c < 2; ++c)
                bf[mi][c] = *(const half8*)(xh +
                    ((((size_t)(c * 96 + m)) * 12 + (k0 >> 3) + quad) * 256 + bc) * 8);
        }
#pragma unroll
        for (int mi = 0; mi < 4; ++mi)
#pragma unroll
            for (int c = 0; c < 2; ++c)
#pragma unroll
                for (int mt = 0; mt < 2; ++mt)
                    acc[mi][c][mt] = __builtin_amdgcn_mfma_f32_16x16x32_f16(
                        af[mi][mt], bf[mi][c], acc[mi][c][mt], 0, 0, 0);
    }

#pragma unroll
    for (int mt = 0; mt < 2; ++mt)
#pragma unroll
        for (int r = 0; r < 4; ++r) {
            const int t = tbase + mt * 16 + quad * 4 + r;
            half8 v;
#pragma unroll
            for (int mi = 0; mi < 4; ++mi) {
                v[2 * mi]     = (half_t)acc[mi][0][mt][r];
                v[2 * mi + 1] = (half_t)acc[mi][1][mt][r];
            }
            *(half8*)(Xp + (((size_t)t * 24 + mg) * 256 + bc) * 8) = v;
        }
}

// ============ stage 2: unified ring DFT (MFMA), all 255 rings ===============
// out[p][bc] = sum_k W_k(p) * Xp[t][k][bc].
// v3: twiddles generated ONCE PER BLOCK into LDS (all 4 waves previously
// computed identical A-fragments in-register -> 4x redundant VALU, ~320
// cyc/k-step vs 78 cyc of MFMA).  Gen phase: ks*1024 (cos,sin) pairs via
// direct __sincosf, written in MFMA-lane order so the hot loop reads each
// lane's 16B fragment with a linear conflict-free ds_read_b128.  Hot loop
// is now 4 ds_read + 4 global loads + 16 MFMA, near-zero VALU.
// Block covers full bc=256; wave tile 64p x 64bc; grid 1020 blocks with
// bijective XCD swizzle (1020 = 8*127+4) so a ring's 4 p-tiles share its
// Xp row in one XCD's L2.
__global__ __launch_bounds__(256) void k_dft(
        const half_t* __restrict__ Xp, float* __restrict__ out) {
    __shared__ half_t Alds[6 * 4 * 64 * 8];      // [kk][pi][lane][8] = 24 KB
    const int bid = blockIdx.x;
    const int xcd = bid & 7, sub = bid >> 3;
    const int wg  = (xcd < 4 ? xcd * 128 : 512 + (xcd - 4) * 127) + sub;
    const int t   = wg >> 2;
    const int p0  = (wg & 3) * 64;
    int n, roff; ring_params(t, n, roff);
    if (p0 >= n) return;

    const int tid = threadIdx.x;
    const int wid = tid >> 6, lane = tid & 63;
    const int row = lane & 15, quad = lane >> 4;

    const int n2 = n >> 1;
    const int mh = min(95, n2);
    const int ks = (2 * (mh + 1) + 31) >> 5;   // 1..6 active 32-wide k-steps

    // ---- gen phase: pair (kk, prow, mloc) -> m = kk*16+mloc, p = p0+prow.
    // LDS position: lane = (mloc>>2)*16 + (prow&15), pi = prow>>4,
    // elem = (mloc&3)*2 -> matches MFMA A-frag lane mapping exactly.
    {
        const float alpha = ring_alpha(t);
        const float invn  = 1.0f / (float)n;
        const int npairs = ks << 10;
        for (int idx = tid; idx < npairs; idx += 256) {
            const int mloc = idx & 15;
            const int prow = (idx >> 4) & 63;
            const int kk   = idx >> 10;
            const int m    = kk * 16 + mloc;
            const float phi = 6.28318530717958647692f * (float)(p0 + prow) * invn
                            + alpha;
            const float sc = (m == 0) ? 1.f : (m < n2) ? 2.f : (m == n2) ? 1.f : 0.f;
            float s, c;
            __sincosf((float)m * phi, &s, &c);
            half2_t v; v[0] = (half_t)(sc * c); v[1] = (half_t)(-sc * s);
            const int pos = (((kk * 4 + (prow >> 4)) * 64
                             + (mloc >> 2) * 16 + (prow & 15)) * 8
                             + (mloc & 3) * 2);
            *(half2_t*)(Alds + pos) = v;
        }
    }
    __syncthreads();

    const half_t* xpb = Xp + (((size_t)t * 24 + quad) * 256 + wid * 64 + row) * 8;
    const half_t* alb = Alds + (size_t)lane * 8;

    f32x4 acc[4][4];                     // [pi][bn]
#pragma unroll
    for (int i = 0; i < 4; ++i)
#pragma unroll
        for (int j = 0; j < 4; ++j) acc[i][j] = (f32x4)0.f;

    auto step = [&](int kk) {
        half8 b[4], a[4];
#pragma unroll
        for (int bn = 0; bn < 4; ++bn)
            b[bn] = *(const half8*)(xpb + kk * 8192 + bn * 128);
#pragma unroll
        for (int pi = 0; pi < 4; ++pi)
            a[pi] = *(const half8*)(alb + (kk * 4 + pi) * 512);
#pragma unroll
        for (int pi = 0; pi < 4; ++pi)
#pragma unroll
            for (int bn = 0; bn < 4; ++bn)
                acc[pi][bn] = __builtin_amdgcn_mfma_f32_16x16x32_f16(
                    a[pi], b[bn], acc[pi][bn], 0, 0, 0);
    };

    if (ks == 6) {                       // bulk path: full unroll, max ILP
#pragma unroll
        for (int kk = 0; kk < 6; ++kk) step(kk);
    } else {                             // small cap rings only
        for (int kk = 0; kk < ks; ++kk) step(kk);
    }

#pragma unroll
    for (int pi = 0; pi < 4; ++pi) {
        const int p = p0 + pi * 16 + quad * 4;
        if (p < n) {                     // n%4==0 -> whole float4 in-bounds
#pragma unroll
            for (int bn = 0; bn < 4; ++bn) {
                const int bc = wid * 64 + bn * 16 + row;
                float4 v = make_float4(acc[pi][bn][0], acc[pi][bn][1],
                                       acc[pi][bn][2], acc[pi][bn][3]);
                *(float4*)(out + (size_t)bc * NPIX + roff + p) = v;
            }
        }
    }
}

// ---------------- launcher --------------------------------------------------
extern "C" void kernel_launch(void* const* d_in, const int* in_sizes, int n_in,
                              void* d_out, int out_size, void* d_ws, size_t ws_size,
                              hipStream_t stream) {
    const float* xr  = (const float*)d_in[0];   // (4,64,96,96)
    const float* xi  = (const float*)d_in[1];   // (4,64,96,96)
    const float* pct = (const float*)d_in[2];   // (96,96,255)
    // d_in[3] (offset) recomputed analytically: off[t][m] = alpha_t * m
    float* out = (float*)d_out;                 // (4,64,49152)

    char* ws = (char*)d_ws;
    half_t* pctT = (half_t*)ws;                          // 96*256*96 halfs
    half_t* xh   = (half_t*)(ws + 4718592);              // 2*96*12*256*8 halfs
    half_t* Xp   = (half_t*)(ws + 4718592 + 9437184);    // 256*24*256*8 halfs

    k_prep<<<dim3(5376), 256, 0, stream>>>(pct, xr, xi, pctT, xh);
    k_leg <<<dim3(768), 256, 0, stream>>>(pctT, xh, Xp);
    k_dft <<<dim3(1020), 256, 0, stream>>>(Xp, out);
}

// Round 4
// 123.057 us; speedup vs baseline: 1.3405x; 1.0873x over previous
//
#include <hip/hip_runtime.h>
#include <hip/hip_bf16.h>
#include <math.h>

#define NLAT 255
#define NPIX 49152
#define PI_F 3.14159265358979323846f

typedef _Float16 half_t;
typedef half_t half8 __attribute__((ext_vector_type(8)));   // A/B frag: 4 VGPRs
typedef half_t half2_t __attribute__((ext_vector_type(2)));
typedef float  f32x4 __attribute__((ext_vector_type(4)));   // C/D frag

// ---------------- ring geometry (NSIDE=64, compile-time closed forms) -------
__device__ __forceinline__ void ring_params(int t, int& n, int& roff) {
    if (t < 63)        { n = 4 * (t + 1); roff = 2 * t * (t + 1); }
    else if (t <= 191) { n = 256;         roff = 8064 + 256 * (t - 63); }
    else               { int w = 255 - t; n = 4 * w; roff = 49152 - 2 * w * (w + 1); }
}

__device__ __forceinline__ float ring_alpha(int t) {
    return (t < 63)   ? PI_F / (4.0f * (float)(t + 1))
         : (t <= 191) ? ((((t - 62) & 1)) ? PI_F / 256.0f : 0.0f)
         :              PI_F / (4.0f * (float)(255 - t));
}

// ============ merged prep kernel ============================================
// blocks [0,768):        pct[m][l][t] -> pctT[m][t][l] fp16 (t padded to 256)
// blocks [768,768+576):  x[bc][l][m]  -> xh[c][m][l/8][bc][l%8] fp16
// v4 x-pack: each block owns a FULL l-chunk of 8 (was: one l per block ->
// every lane stored 2B into a 16B granule shared with 7 other blocks ->
// partial-line write amplification).  Now: float4 global reads -> 33KB LDS
// (stride-33 padded, conflict-free transpose) -> one contiguous half8 (16B)
// store per lane, wave-coalesced 512B.  4608 blocks -> 576.
__global__ __launch_bounds__(256) void k_prep(
        const float* __restrict__ pct,
        const float* __restrict__ xr, const float* __restrict__ xi,
        half_t* __restrict__ pctT, half_t* __restrict__ xh) {
    __shared__ float smem[8 * 32 * 33];  // 8448 floats; pct path uses 96*33
    const int bx  = blockIdx.x;
    const int tid = threadIdx.x;

    if (bx < 768) {                     // ---- pct transpose ----
        const int m = bx >> 3, t0 = (bx & 7) * 32;
        for (int idx = tid; idx < 96 * 32; idx += 256) {
            int l = idx >> 5, tt = idx & 31, t = t0 + tt;
            smem[l * 33 + tt] = (t < NLAT) ? pct[((size_t)m * 96 + l) * NLAT + t] : 0.f;
        }
        __syncthreads();
        for (int idx = tid; idx < 96 * 32; idx += 256) {
            int tt = idx / 96, l = idx - tt * 96;
            pctT[((size_t)m * 256 + t0 + tt) * 96 + l] = (half_t)smem[l * 33 + tt];
        }
    } else {                            // ---- x pack/transpose (l-chunked) ----
        const int id   = bx - 768;      // 0..575
        const int lc   = id % 12;
        const int bc0  = ((id / 12) & 7) * 32;
        const int z    = id / 96;       // comp*3 + mtile
        const int comp = z / 3, m0 = (z % 3) * 32;
        const float* in = comp ? xi : xr;

        // phase 1: load 8l x 32bc x 32m floats as float4 (8 iters/thread)
#pragma unroll
        for (int it = 0; it < 8; ++it) {
            int idx = tid + it * 256;            // over 2048 float4s
            int m4  = idx & 7;                   // float4 index within 32 m
            int b   = (idx >> 3) & 31;
            int li  = idx >> 8;
            float4 v = *(const float4*)(in
                + (size_t)(bc0 + b) * 9216 + (lc * 8 + li) * 96 + m0 + m4 * 4);
            float* s = &smem[li * 1056 + b * 33 + m4 * 4];
            s[0] = v.x; s[1] = v.y; s[2] = v.z; s[3] = v.w;
        }
        __syncthreads();

        // phase 2: each lane gathers 8 l's for one (m,bc) -> one half8 store
#pragma unroll
        for (int j = 0; j < 4; ++j) {
            int ml = (tid >> 5) + j * 8;
            int bc = tid & 31;
            half8 v;
#pragma unroll
            for (int li = 0; li < 8; ++li)
                v[li] = (half_t)smem[li * 1056 + bc * 33 + ml];
            *(half8*)(xh + ((((size_t)(comp * 96 + m0 + ml)) * 12 + lc) * 256
                            + bc0 + bc) * 8) = v;
        }
    }
}

// ============ stage 1: Legendre GEMMs (MFMA) ================================
// For m-group of 4: C[t][bc] = sum_l pctT[m][t][l] * xh[c][m][l][bc], K=96.
// Block tile M=64 x N=32, 4 waves (2 in t, 2 in bc), wave tile 32x16.
// Grid flattened to 768 with chunked XCD mapping (96 consecutive wg per XCD
// = 3 complete mg groups, working set 2.4MB < 4MB L2).
__global__ __launch_bounds__(256) void k_leg(
        const half_t* __restrict__ pctT, const half_t* __restrict__ xh,
        half_t* __restrict__ Xp) {
    const int b   = blockIdx.x;
    const int wg  = (b & 7) * 96 + (b >> 3);   // bijective, 768 = 8*96
    const int mg  = wg >> 5;                   // 0..23
    const int rem = wg & 31;
    const int t0  = (rem >> 3) * 64;
    const int bc0 = (rem & 7) * 32;
    const int wid = threadIdx.x >> 6, lane = threadIdx.x & 63;
    const int wm = wid & 1, wn = wid >> 1;
    const int row = lane & 15, quad = lane >> 4;
    const int tbase = t0 + wm * 32;
    const int bc    = bc0 + wn * 16 + row;

    f32x4 acc[4][2][2];                  // [mi][comp][mt]
#pragma unroll
    for (int a = 0; a < 4; ++a)
#pragma unroll
        for (int bb = 0; bb < 2; ++bb)
#pragma unroll
            for (int d = 0; d < 2; ++d) acc[a][bb][d] = (f32x4)0.f;

#pragma unroll
    for (int k0 = 0; k0 < 96; k0 += 32) {
        const int kA = k0 + quad * 8;
        half8 af[4][2], bf[4][2];
#pragma unroll
        for (int mi = 0; mi < 4; ++mi) {
            const int m = mg * 4 + mi;
#pragma unroll
            for (int mt = 0; mt < 2; ++mt)
                af[mi][mt] = *(const half8*)(pctT +
                    ((size_t)m * 256 + tbase + mt * 16 + row) * 96 + kA);
#pragma unroll
            for (int c = 0; c < 2; ++c)
                bf[mi][c] = *(const half8*)(xh +
                    ((((size_t)(c * 96 + m)) * 12 + (k0 >> 3) + quad) * 256 + bc) * 8);
        }
#pragma unroll
        for (int mi = 0; mi < 4; ++mi)
#pragma unroll
            for (int c = 0; c < 2; ++c)
#pragma unroll
                for (int mt = 0; mt < 2; ++mt)
                    acc[mi][c][mt] = __builtin_amdgcn_mfma_f32_16x16x32_f16(
                        af[mi][mt], bf[mi][c], acc[mi][c][mt], 0, 0, 0);
    }

#pragma unroll
    for (int mt = 0; mt < 2; ++mt)
#pragma unroll
        for (int r = 0; r < 4; ++r) {
            const int t = tbase + mt * 16 + quad * 4 + r;
            half8 v;
#pragma unroll
            for (int mi = 0; mi < 4; ++mi) {
                v[2 * mi]     = (half_t)acc[mi][0][mt][r];
                v[2 * mi + 1] = (half_t)acc[mi][1][mt][r];
            }
            *(half8*)(Xp + (((size_t)t * 24 + mg) * 256 + bc) * 8) = v;
        }
}

// ============ stage 2: unified ring DFT (MFMA), all 255 rings ===============
// out[p][bc] = sum_k W_k(p) * Xp[t][k][bc].
// Twiddles generated once per block into LDS (MFMA-lane order -> linear
// conflict-free ds_read_b128 in the hot loop).  v4: the first two k-planes'
// Xp B-loads are issued BEFORE the gen phase (independent of LDS) so HBM
// latency hides under the transcendental work (T14 issue-early).
// Block covers full bc=256; wave tile 64p x 64bc; grid 1020 blocks with
// bijective XCD swizzle (1020 = 8*127+4) so a ring's 4 p-tiles share its
// Xp row in one XCD's L2.
__global__ __launch_bounds__(256) void k_dft(
        const half_t* __restrict__ Xp, float* __restrict__ out) {
    __shared__ half_t Alds[6 * 4 * 64 * 8];      // [kk][pi][lane][8] = 24 KB
    const int bid = blockIdx.x;
    const int xcd = bid & 7, sub = bid >> 3;
    const int wg  = (xcd < 4 ? xcd * 128 : 512 + (xcd - 4) * 127) + sub;
    const int t   = wg >> 2;
    const int p0  = (wg & 3) * 64;
    int n, roff; ring_params(t, n, roff);
    if (p0 >= n) return;

    const int tid = threadIdx.x;
    const int wid = tid >> 6, lane = tid & 63;
    const int row = lane & 15, quad = lane >> 4;

    const int n2 = n >> 1;
    const int mh = min(95, n2);
    const int ks = (2 * (mh + 1) + 31) >> 5;   // 1..6 active 32-wide k-steps

    const half_t* xpb = Xp + (((size_t)t * 24 + quad) * 256 + wid * 64 + row) * 8;

    // ---- issue-early: first two k-planes of B, independent of LDS gen ----
    half8 bpre[2][4];
#pragma unroll
    for (int kk = 0; kk < 2; ++kk)
#pragma unroll
        for (int bn = 0; bn < 4; ++bn)
            bpre[kk][bn] = *(const half8*)(xpb + kk * 8192 + bn * 128);

    // ---- gen phase: pair (kk, prow, mloc) -> m = kk*16+mloc, p = p0+prow.
    // LDS position: lane = (mloc>>2)*16 + (prow&15), pi = prow>>4,
    // elem = (mloc&3)*2 -> matches MFMA A-frag lane mapping exactly.
    {
        const float alpha = ring_alpha(t);
        const float invn  = 1.0f / (float)n;
        const int npairs = ks << 10;
        for (int idx = tid; idx < npairs; idx += 256) {
            const int mloc = idx & 15;
            const int prow = (idx >> 4) & 63;
            const int kk   = idx >> 10;
            const int m    = kk * 16 + mloc;
            const float phi = 6.28318530717958647692f * (float)(p0 + prow) * invn
                            + alpha;
            const float sc = (m == 0) ? 1.f : (m < n2) ? 2.f : (m == n2) ? 1.f : 0.f;
            float s, c;
            __sincosf((float)m * phi, &s, &c);
            half2_t v; v[0] = (half_t)(sc * c); v[1] = (half_t)(-sc * s);
            const int pos = (((kk * 4 + (prow >> 4)) * 64
                             + (mloc >> 2) * 16 + (prow & 15)) * 8
                             + (mloc & 3) * 2);
            *(half2_t*)(Alds + pos) = v;
        }
    }
    __syncthreads();

    const half_t* alb = Alds + (size_t)lane * 8;

    f32x4 acc[4][4];                     // [pi][bn]
#pragma unroll
    for (int i = 0; i < 4; ++i)
#pragma unroll
        for (int j = 0; j < 4; ++j) acc[i][j] = (f32x4)0.f;

    auto step = [&](int kk, const half8 b[4]) {
        half8 a[4];
#pragma unroll
        for (int pi = 0; pi < 4; ++pi)
            a[pi] = *(const half8*)(alb + (kk * 4 + pi) * 512);
#pragma unroll
        for (int pi = 0; pi < 4; ++pi)
#pragma unroll
            for (int bn = 0; bn < 4; ++bn)
                acc[pi][bn] = __builtin_amdgcn_mfma_f32_16x16x32_f16(
                    a[pi], b[bn], acc[pi][bn], 0, 0, 0);
    };
    auto ldb = [&](int kk, half8 b[4]) {
#pragma unroll
        for (int bn = 0; bn < 4; ++bn)
            b[bn] = *(const half8*)(xpb + kk * 8192 + bn * 128);
    };

    if (ks == 6) {                       // bulk path: full unroll, max ILP
        step(0, bpre[0]);
        step(1, bpre[1]);
#pragma unroll
        for (int kk = 2; kk < 6; ++kk) {
            half8 b[4]; ldb(kk, b); step(kk, b);
        }
    } else {                             // small cap rings only
        step(0, bpre[0]);
        if (ks > 1) step(1, bpre[1]);
        for (int kk = 2; kk < ks; ++kk) {
            half8 b[4]; ldb(kk, b); step(kk, b);
        }
    }

#pragma unroll
    for (int pi = 0; pi < 4; ++pi) {
        const int p = p0 + pi * 16 + quad * 4;
        if (p < n) {                     // n%4==0 -> whole float4 in-bounds
#pragma unroll
            for (int bn = 0; bn < 4; ++bn) {
                const int bc = wid * 64 + bn * 16 + row;
                float4 v = make_float4(acc[pi][bn][0], acc[pi][bn][1],
                                       acc[pi][bn][2], acc[pi][bn][3]);
                *(float4*)(out + (size_t)bc * NPIX + roff + p) = v;
            }
        }
    }
}

// ---------------- launcher --------------------------------------------------
extern "C" void kernel_launch(void* const* d_in, const int* in_sizes, int n_in,
                              void* d_out, int out_size, void* d_ws, size_t ws_size,
                              hipStream_t stream) {
    const float* xr  = (const float*)d_in[0];   // (4,64,96,96)
    const float* xi  = (const float*)d_in[1];   // (4,64,96,96)
    const float* pct = (const float*)d_in[2];   // (96,96,255)
    // d_in[3] (offset) recomputed analytically: off[t][m] = alpha_t * m
    float* out = (float*)d_out;                 // (4,64,49152)

    char* ws = (char*)d_ws;
    half_t* pctT = (half_t*)ws;                          // 96*256*96 halfs
    half_t* xh   = (half_t*)(ws + 4718592);              // 2*96*12*256*8 halfs
    half_t* Xp   = (half_t*)(ws + 4718592 + 9437184);    // 256*24*256*8 halfs

    k_prep<<<dim3(768 + 576), 256, 0, stream>>>(pct, xr, xi, pctT, xh);
    k_leg <<<dim3(768), 256, 0, stream>>>(pctT, xh, Xp);
    k_dft <<<dim3(1020), 256, 0, stream>>>(Xp, out);
}